// Round 16
// baseline (299.636 us; speedup 1.0000x reference)
//
#include <hip/hip_runtime.h>
#include <hip/hip_bf16.h>
#include <stdint.h>

#define DEV static __device__ __forceinline__

typedef __attribute__((ext_vector_type(8))) short bf16x8;
typedef __attribute__((ext_vector_type(4))) float f32x4;
typedef unsigned int u32;

static constexpr int T = 4096;
static constexpr int BATCH = 8;
static constexpr int DM = 1024;            // d_model
static constexpr int M1 = BATCH * T;       // 32768 rows into GEMM1
static constexpr int M2 = BATCH * (T + 1); // 32776 rows into GEMM2
static constexpr int M2P = 129 * 256;      // 33024 padded rows for S (256-row tiles)
static constexpr int NCH = 64;
static constexpr int CL = T / NCH;
static constexpr int NT = 16;              // K tiles (BK=64, K=1024)

DEV unsigned short f2bf(float f) {
  union { float f; unsigned u; } v; v.f = f;
  unsigned u = v.u;
  return (unsigned short)((u + 0x7fffu + ((u >> 16) & 1u)) >> 16);
}
DEV float bf2f(unsigned short s) {
  union { unsigned u; float f; } v; v.u = ((unsigned)s) << 16;
  return v.f;
}

// async global->LDS, 16B per lane. lds dest wave-uniform; g per-lane.
DEV void gl_lds16(const unsigned short* g, void* lds) {
  __builtin_amdgcn_global_load_lds(
      (const __attribute__((address_space(1))) u32*)g,
      (__attribute__((address_space(3))) u32*)lds,
      16, 0, 0);
}

// scheduler-invisible LDS read (rule 18: caller must lgkmcnt(0)+sched_barrier(0))
DEV bf16x8 ds_read128(unsigned byte_off) {
  bf16x8 r;
  asm volatile("ds_read_b128 %0, %1" : "=v"(r) : "v"(byte_off));
  return r;
}

// ---------------- fp32 -> bf16 convert of inputs ----------------
__global__ void k_cvt_x(const float4* __restrict__ x, ushort4* __restrict__ o) {
  int i = blockIdx.x * 256 + threadIdx.x;
  float4 v = x[i];
  ushort4 r;
  r.x = f2bf(v.x); r.y = f2bf(v.y); r.z = f2bf(v.z); r.w = f2bf(v.w);
  o[i] = r;
}

// ------------- transpose + convert weights: Wt[n][k] = W[k][n] -------------
__global__ void k_transpose(const float* __restrict__ w0, const float* __restrict__ w1,
                            unsigned short* __restrict__ t0, unsigned short* __restrict__ t1) {
  __shared__ float tile[32][33];
  const float* src = blockIdx.z ? w1 : w0;
  unsigned short* dst = blockIdx.z ? t1 : t0;
  int bx = blockIdx.x * 32;
  int by = blockIdx.y * 32;
  int tx = threadIdx.x & 31, ty = threadIdx.x >> 5;
#pragma unroll
  for (int r = 0; r < 32; r += 8)
    tile[ty + r][tx] = src[(by + ty + r) * DM + bx + tx];
  __syncthreads();
#pragma unroll
  for (int r = 0; r < 32; r += 8)
    dst[(bx + ty + r) * DM + by + tx] = f2bf(tile[tx][ty + r]);
}

// ---------------- bf16 MFMA GEMM: C = A @ Wt^T + bias ----------------
// m201-faithful 8-phase derived-waits schedule. 256x256 tile, BK=64, 8 waves
// (2M x 4N). Per-wave output INTERLEAVED across halves:
//   row(mf) = (mf>>2)*128 + (mf&3)*32 + wm*16 + lo
//   col(nf) = (nf>>1)*128 + (nf&1)*64 + wn*16 + hi*4 + j
// so phase (mh,nh) has ALL waves reading only A-half mh + B-half nh
// (12 ds_read_b128) + 16 MFMA -> each half-region frees after its last
// reader phase, letting tile t+2/t+3 stream in 1 half per phase:
//   p1:t1.A1 p2:t1.B1 p3:t2.A0 p4:t2.B0+vmcnt(4) p5:t2.A1 p6:t2.B1
//   p7:t3.A0 p8:t3.B0+vmcnt(4)     (every stage barrier-separated from
// its region's last reader; vmcnt(4) confirms the next tile exactly).
// LDS 128 KiB: [slot][op][half][128 rows][64 k] bf16, phys k-slot =
// (kh*4+hi)^(row&7) (2-way = free), inverse-swizzled gl_lds source.
// MODE 0: bf16 out. MODE 1: fp32 out, row guard.
template <int MODE>
__global__ __launch_bounds__(512, 2) void k_gemm(const unsigned short* __restrict__ A16,
                                                 const unsigned short* __restrict__ Bt16,
                                                 const float* __restrict__ bias,
                                                 unsigned short* __restrict__ outb,
                                                 float* __restrict__ outf, int Mvalid) {
  __shared__ char smem[131072];  // 2 slots x (A 32K + B 32K)

  const int tid = threadIdx.x;
  const int w = tid >> 6, l = tid & 63;
  const int wm = w >> 2, wn = w & 3;   // 2M x 4N wave grid
  const int lo = l & 15, hi = l >> 4;

  // bijective XCD swizzle (m204 general form; nwg = 512 or 516)
  const int nwg = gridDim.x, orig = blockIdx.x;
  const int q8 = nwg >> 3, r8 = nwg & 7;
  const int xcd = orig & 7, idx = orig >> 3;
  const int wg = (xcd < r8 ? xcd * (q8 + 1) : r8 * (q8 + 1) + (xcd - r8) * q8) + idx;
  const int bm = wg >> 2, bn = wg & 3;
  const int blockM = bm * 256;
  const int blockN = bn * 256;

  f32x4 acc[8][4];
#pragma unroll
  for (int m = 0; m < 8; m++)
#pragma unroll
    for (int n = 0; n < 4; n++) acc[m][n] = (f32x4){0.f, 0.f, 0.f, 0.f};

  // ---- staging geometry: half = 128 rows x 64 k = 16KB = 2 gl_lds/thread.
  // load j: row = half*128 + j*64 + w*8 + (l>>3); LDS dest linear (lane*16);
  // source k-slot inverse-swizzled: (l&7)^((l>>3)&7)  [row&7 == (l>>3)&7].
  const int srcs = (l & 7) ^ ((l >> 3) & 7);
  const unsigned short* pG[2][2];  // [op][j]
#pragma unroll
  for (int j = 0; j < 2; j++) {
    const int rr = j * 64 + w * 8 + (l >> 3);
    pG[0][j] = A16 + (size_t)(blockM + rr) * DM + srcs * 8;
    pG[1][j] = Bt16 + (size_t)(blockN + rr) * DM + srcs * 8;
  }

#define STAGE(tt, OP, H)                                                        \
  do {                                                                          \
    char* d_ = smem + ((tt) & 1) * 65536 + (OP) * 32768 + (H) * 16384 + w * 1024; \
    gl_lds16(pG[OP][0] + (size_t)(H) * 128 * DM + (size_t)(tt) * 64, d_);       \
    gl_lds16(pG[OP][1] + (size_t)(H) * 128 * DM + (size_t)(tt) * 64, d_ + 8192); \
  } while (0)

  // ---- fragment read offsets (bytes). phys k-slot = (kh*4+hi)^(lo&7)
  // (row&7 == lo&7 since all row bases are multiples of 8).
  const unsigned ldsbase =
      (unsigned)(size_t)(__attribute__((address_space(3))) char*)smem;
  unsigned offA[4], offB[2], phy[2];
#pragma unroll
  for (int kh = 0; kh < 2; kh++) phy[kh] = (unsigned)(((kh * 4 + hi) ^ (lo & 7)) * 16);
#pragma unroll
  for (int mf = 0; mf < 4; mf++) offA[mf] = (unsigned)((mf * 32 + wm * 16 + lo) * 128);
#pragma unroll
  for (int nf = 0; nf < 2; nf++) offB[nf] = (unsigned)((nf * 64 + wn * 16 + lo) * 128);

#define VM4 asm volatile("s_waitcnt vmcnt(4)" ::: "memory")
#define VM0 asm volatile("s_waitcnt vmcnt(0)" ::: "memory")

#define PH(SLOT, MH, NH, STG, WAIT)                                               \
  do {                                                                           \
    const unsigned bA_ = ldsbase + (SLOT) * 65536u + (MH) * 16384u;              \
    const unsigned bB_ = ldsbase + (SLOT) * 65536u + 32768u + (NH) * 16384u;     \
    bf16x8 aq_[4][2], bq_[2][2];                                                 \
    _Pragma("unroll") for (int kh = 0; kh < 2; kh++) {                           \
      _Pragma("unroll") for (int nf = 0; nf < 2; nf++)                           \
        bq_[nf][kh] = ds_read128(bB_ + offB[nf] + phy[kh]);                      \
      _Pragma("unroll") for (int mf = 0; mf < 4; mf++)                           \
        aq_[mf][kh] = ds_read128(bA_ + offA[mf] + phy[kh]);                      \
    }                                                                            \
    STG;                                                                         \
    WAIT;                                                                        \
    __builtin_amdgcn_s_barrier();                                                \
    asm volatile("s_waitcnt lgkmcnt(0)" ::: "memory");                           \
    __builtin_amdgcn_sched_barrier(0);                                           \
    __builtin_amdgcn_s_setprio(1);                                               \
    _Pragma("unroll") for (int kh = 0; kh < 2; kh++)                             \
      _Pragma("unroll") for (int mf = 0; mf < 4; mf++)                           \
        _Pragma("unroll") for (int nf = 0; nf < 2; nf++)                         \
          acc[(MH) * 4 + mf][(NH) * 2 + nf] =                                    \
              __builtin_amdgcn_mfma_f32_16x16x32_bf16(                           \
                  bq_[nf][kh], aq_[mf][kh], acc[(MH) * 4 + mf][(NH) * 2 + nf],   \
                  0, 0, 0);                                                      \
    __builtin_amdgcn_s_setprio(0);                                               \
    __builtin_amdgcn_s_barrier();                                                \
  } while (0)

  // prologue: t0 all 4 halves (8 loads), t1.A0,B0 (4 loads); confirm t0.
  STAGE(0, 0, 0); STAGE(0, 1, 0); STAGE(0, 0, 1); STAGE(0, 1, 1);
  STAGE(1, 0, 0); STAGE(1, 1, 0);
  VM4;  // oldest 8 (all t0) landed; t1.A0,B0 stay in flight
  __builtin_amdgcn_s_barrier();

  for (int i = 0; i < NT / 2; ++i) {
    const int t1 = 2 * i + 1, t2 = 2 * i + 2, t3 = 2 * i + 3;
    const bool g2 = (t2 < NT), g3 = (t3 < NT);
    PH(0, 0, 0, STAGE(t1, 0, 1), );                               // p1
    PH(0, 0, 1, STAGE(t1, 1, 1), );                               // p2
    PH(0, 1, 0, if (g2) STAGE(t2, 0, 0), );                       // p3
    PH(0, 1, 1, if (g2) STAGE(t2, 1, 0), if (g2) { VM4; } else { VM0; });  // p4
    PH(1, 0, 0, if (g2) STAGE(t2, 0, 1), );                       // p5
    PH(1, 0, 1, if (g2) STAGE(t2, 1, 1), );                       // p6
    PH(1, 1, 0, if (g3) STAGE(t3, 0, 0), );                       // p7
    PH(1, 1, 1, if (g3) STAGE(t3, 1, 0), if (g3) { VM4; } else { VM0; });  // p8
  }
#undef PH
#undef STAGE

  // epilogue: swapped mfma(B,A) mapping (r7/r8-verified), interleaved tiling:
  // row = blockM + (mf>>2)*128 + (mf&3)*32 + wm*16 + lo
  // col = blockN + (nf>>1)*128 + (nf&1)*64 + wn*16 + hi*4 + j
#pragma unroll
  for (int mf = 0; mf < 8; mf++) {
    const int row = blockM + (mf >> 2) * 128 + (mf & 3) * 32 + wm * 16 + lo;
    if (MODE == 1 && row >= Mvalid) continue;
#pragma unroll
    for (int nf = 0; nf < 4; nf++) {
      const int col = blockN + (nf >> 1) * 128 + (nf & 1) * 64 + wn * 16 + hi * 4;
      const float4 bv = *(const float4*)(bias + col);
      if (MODE == 0) {
        ushort4 o;
        o.x = f2bf(acc[mf][nf][0] + bv.x);
        o.y = f2bf(acc[mf][nf][1] + bv.y);
        o.z = f2bf(acc[mf][nf][2] + bv.z);
        o.w = f2bf(acc[mf][nf][3] + bv.w);
        *(ushort4*)(outb + (size_t)row * DM + col) = o;
      } else {
        float4 o;
        o.x = acc[mf][nf][0] + bv.x;
        o.y = acc[mf][nf][1] + bv.y;
        o.z = acc[mf][nf][2] + bv.z;
        o.w = acc[mf][nf][3] + bv.w;
        *(float4*)(outf + (size_t)row * DM + col) = o;
      }
    }
  }
}

// ---------------- scan phase A (vectorized: 8 ch/thread) ----------------
__global__ void k_scan_partial(const unsigned short* __restrict__ proj,
                               const float* __restrict__ logit,
                               const float* __restrict__ z0,
                               float* __restrict__ chunkend) {
  const int b = blockIdx.x >> 6, c = blockIdx.x & 63;
  const int ch0 = threadIdx.x * 8;
  const float a = 1.f / (1.f + expf(-logit[ch0 >> 6]));
  const int t0 = c * CL;
  const unsigned short* p = proj + (size_t)(b * T + t0) * DM + ch0;
  float pprev[8], s[8];
  if (t0 == 0) {
#pragma unroll
    for (int k = 0; k < 8; k++) pprev[k] = z0[ch0 + k];
  } else {
    bf16x8 v = *(const bf16x8*)(p - DM);
#pragma unroll
    for (int k = 0; k < 8; k++) pprev[k] = bf2f((unsigned short)v[k]);
  }
#pragma unroll
  for (int k = 0; k < 8; k++) s[k] = 0.f;
  for (int j = 0; j < CL; j++) {
    bf16x8 v = *(const bf16x8*)(p + (size_t)j * DM);
#pragma unroll
    for (int k = 0; k < 8; k++) {
      float pv = bf2f((unsigned short)v[k]);
      s[k] = a * s[k] + (1.f - a) * (pv - pprev[k]);
      pprev[k] = pv;
    }
  }
  float* o = chunkend + (size_t)(b * NCH + c) * DM + ch0;
#pragma unroll
  for (int k = 0; k < 4; k++) ((float2*)o)[k] = make_float2(s[2 * k], s[2 * k + 1]);
}

// ---------------- scan phase B (vectorized: 4 ch/thread) ----------------
__global__ void k_scan_combine(const float* __restrict__ chunkend,
                               const float* __restrict__ logit,
                               const float* __restrict__ v0,
                               float* __restrict__ enter) {
  const int b = blockIdx.x;
  const int ch0 = threadIdx.x * 4;
  const float a = 1.f / (1.f + expf(-logit[ch0 >> 6]));
  const float a2 = a * a, a4 = a2 * a2, a8 = a4 * a4, a16 = a8 * a8, a32 = a16 * a16;
  const float aL = a32 * a32;  // a^64
  float4 e = *(const float4*)(v0 + ch0);
  *(float4*)(enter + (size_t)(b * NCH) * DM + ch0) = e;
  for (int c = 1; c < NCH; c++) {
    const float4 ce = *(const float4*)(chunkend + (size_t)(b * NCH + c - 1) * DM + ch0);
    e.x = aL * e.x + ce.x;
    e.y = aL * e.y + ce.y;
    e.z = aL * e.z + ce.z;
    e.w = aL * e.w + ce.w;
    *(float4*)(enter + (size_t)(b * NCH + c) * DM + ch0) = e;
  }
}

// ---------------- scan phase C (vectorized: 8 ch/thread) ----------------
__global__ void k_scan_final(const unsigned short* __restrict__ proj,
                             const float* __restrict__ logit,
                             const float* __restrict__ z0,
                             const float* __restrict__ v0,
                             const float* __restrict__ enter,
                             unsigned short* __restrict__ S) {
  const int b = blockIdx.x >> 6, c = blockIdx.x & 63;
  const int ch0 = threadIdx.x * 8;
  const float a = 1.f / (1.f + expf(-logit[ch0 >> 6]));
  const int t0 = c * CL;
  const unsigned short* p = proj + (size_t)(b * T + t0) * DM + ch0;
  unsigned short* so = S + (size_t)(b * (T + 1) + t0 + 1) * DM + ch0;
  float pprev[8], s[8];
  if (t0 == 0) {
#pragma unroll
    for (int k = 0; k < 8; k++) pprev[k] = z0[ch0 + k];
  } else {
    bf16x8 v = *(const bf16x8*)(p - DM);
#pragma unroll
    for (int k = 0; k < 8; k++) pprev[k] = bf2f((unsigned short)v[k]);
  }
  {
    const float* e = enter + (size_t)(b * NCH + c) * DM + ch0;
#pragma unroll
    for (int k = 0; k < 8; k++) s[k] = e[k];
  }
  if (c == 0) {
    bf16x8 r;
#pragma unroll
    for (int k = 0; k < 8; k++) r[k] = (short)f2bf(v0[ch0 + k]);
    *(bf16x8*)(S + (size_t)b * (T + 1) * DM + ch0) = r;  // row 0 = v0
  }
  for (int j = 0; j < CL; j++) {
    bf16x8 v = *(const bf16x8*)(p + (size_t)j * DM);
    bf16x8 r;
#pragma unroll
    for (int k = 0; k < 8; k++) {
      float pv = bf2f((unsigned short)v[k]);
      s[k] = a * s[k] + (1.f - a) * (pv - pprev[k]);
      pprev[k] = pv;
      r[k] = (short)f2bf(s[k]);
    }
    *(bf16x8*)(so + (size_t)j * DM) = r;
  }
}

extern "C" void kernel_launch(void* const* d_in, const int* in_sizes, int n_in,
                              void* d_out, int out_size, void* d_ws, size_t ws_size,
                              hipStream_t stream) {
  const float* inputs = (const float*)d_in[0];
  const float* z0     = (const float*)d_in[1];
  const float* W_in   = (const float*)d_in[2];
  const float* b_in   = (const float*)d_in[3];
  const float* W_out  = (const float*)d_in[4];
  const float* b_out  = (const float*)d_in[5];
  const float* slogit = (const float*)d_in[6];
  const float* v0     = (const float*)d_in[7];
  float* out = (float*)d_out;

  char* ws = (char*)d_ws;
  unsigned short* X16   = (unsigned short*)(ws);                 // 67,108,864 B
  unsigned short* P16   = (unsigned short*)(ws + 67108864);      // 67,108,864 B
  unsigned short* S16   = (unsigned short*)(ws + 134217728);     // 67,633,152 B (33024 rows)
  unsigned short* WTin  = (unsigned short*)(ws + 201850880);     // 2,097,152 B
  unsigned short* WTout = (unsigned short*)(ws + 203948032);     // 2,097,152 B
  float* chunkend       = (float*)(ws + 206045184);              // 2,097,152 B
  float* enter          = (float*)(ws + 208142336);              // 2,097,152 B

  // 1. convert inputs to bf16
  k_cvt_x<<<32768, 256, 0, stream>>>((const float4*)inputs, (ushort4*)X16);
  // 2. transpose+convert both weights
  k_transpose<<<dim3(32, 32, 2), 256, 0, stream>>>(W_in, W_out, WTin, WTout);
  // 3. GEMM1 (8-phase): proj = inputs @ W_in + b_in (bf16 out), 128x4 = 512 wgs
  k_gemm<0><<<dim3((M1 / 256) * 4), 512, 0, stream>>>(X16, WTin, b_in, P16, nullptr, M1);
  // 4. scan: temporal diff + exponential smoothing
  k_scan_partial<<<dim3(BATCH * NCH), 128, 0, stream>>>(P16, slogit, z0, chunkend);
  k_scan_combine<<<dim3(BATCH), 256, 0, stream>>>(chunkend, slogit, v0, enter);
  k_scan_final<<<dim3(BATCH * NCH), 128, 0, stream>>>(P16, slogit, z0, v0, enter, S16);
  // (pad rows of S16 are unwritten poison: finite bf16, outputs row-guarded)
  // 5. GEMM2 (8-phase): out = S @ W_out + b_out (fp32, 32776 valid of 33024), 129x4 = 516 wgs
  k_gemm<1><<<dim3((M2P / 256) * 4), 512, 0, stream>>>(S16, WTout, b_out, nullptr, out, M2);
}

// Round 17
// 274.311 us; speedup vs baseline: 1.0923x; 1.0923x over previous
//
#include <hip/hip_runtime.h>
#include <hip/hip_bf16.h>
#include <stdint.h>

#define DEV static __device__ __forceinline__

typedef __attribute__((ext_vector_type(8))) short bf16x8;
typedef __attribute__((ext_vector_type(4))) float f32x4;
typedef unsigned int u32;

static constexpr int T = 4096;
static constexpr int BATCH = 8;
static constexpr int DM = 1024;            // d_model
static constexpr int M1 = BATCH * T;       // 32768 rows into GEMM1
static constexpr int M2 = BATCH * (T + 1); // 32776 rows into GEMM2
static constexpr int M2P = 129 * 256;      // 33024 padded rows for S (256-row tiles)
static constexpr int NCH = 64;
static constexpr int CL = T / NCH;
static constexpr int NT = 32;              // K tiles (BK=32, K=1024)

DEV unsigned short f2bf(float f) {
  union { float f; unsigned u; } v; v.f = f;
  unsigned u = v.u;
  return (unsigned short)((u + 0x7fffu + ((u >> 16) & 1u)) >> 16);
}
DEV float bf2f(unsigned short s) {
  union { unsigned u; float f; } v; v.u = ((unsigned)s) << 16;
  return v.f;
}

// async global->LDS, 16B per lane. lds dest wave-uniform; g per-lane.
DEV void gl_lds16(const unsigned short* g, unsigned short* lds) {
  __builtin_amdgcn_global_load_lds(
      (const __attribute__((address_space(1))) u32*)g,
      (__attribute__((address_space(3))) u32*)lds,
      16, 0, 0);
}

// ---------------- fp32 -> bf16 convert of inputs ----------------
__global__ void k_cvt_x(const float4* __restrict__ x, ushort4* __restrict__ o) {
  int i = blockIdx.x * 256 + threadIdx.x;
  float4 v = x[i];
  ushort4 r;
  r.x = f2bf(v.x); r.y = f2bf(v.y); r.z = f2bf(v.z); r.w = f2bf(v.w);
  o[i] = r;
}

// ------------- transpose + convert weights: Wt[n][k] = W[k][n] -------------
__global__ void k_transpose(const float* __restrict__ w0, const float* __restrict__ w1,
                            unsigned short* __restrict__ t0, unsigned short* __restrict__ t1) {
  __shared__ float tile[32][33];
  const float* src = blockIdx.z ? w1 : w0;
  unsigned short* dst = blockIdx.z ? t1 : t0;
  int bx = blockIdx.x * 32;
  int by = blockIdx.y * 32;
  int tx = threadIdx.x & 31, ty = threadIdx.x >> 5;
#pragma unroll
  for (int r = 0; r < 32; r += 8)
    tile[ty + r][tx] = src[(by + ty + r) * DM + bx + tx];
  __syncthreads();
#pragma unroll
  for (int r = 0; r < 32; r += 8)
    dst[(bx + ty + r) * DM + by + tx] = f2bf(tile[tx][ty + r]);
}

// ---------------- bf16 MFMA GEMM: C = A @ Wt^T + bias ----------------
// r17: LDS-bytes/FLOP reduction. Same 256x128 tile, BK=32, single-drain
// 2-phase skeleton as r13 — but 4 waves (2M x 2N), per-wave 128x64 output
// (m=8 x n=4 frags): 12 ds_read_b128 per 32 MFMA = 0.375 reads/MFMA
// (r13: 8 per 16 = 0.5). LDS 48 KiB dbuf; gl_lds staging, XOR swizzle
// phys = g ^ ((row>>1)&3), inverse-swizzled global source.
// MODE 0: bf16 out. MODE 1: fp32 out, row guard.
template <int MODE>
__global__ __launch_bounds__(256, 2) void k_gemm(const unsigned short* __restrict__ A16,
                                                 const unsigned short* __restrict__ Bt16,
                                                 const float* __restrict__ bias,
                                                 unsigned short* __restrict__ outb,
                                                 float* __restrict__ outf, int Mvalid) {
  // buf b at b*12288 elems: A [256r][32k] at +0, B [128r][32k] at +8192
  __shared__ unsigned short lds[24576];  // 48 KiB

  const int tid = threadIdx.x;
  const int w = tid >> 6, l = tid & 63;
  const int wm = w >> 1, wn = w & 1;   // 2M x 2N wave grid, per-wave 128x64
  const int lo = l & 15, hi = l >> 4;

  // bijective XCD swizzle (nwg % 8 == 0: 1024 and 1032)
  const int nwg = gridDim.x, orig = blockIdx.x;
  const int cpx = nwg >> 3;
  const int wg = (orig & 7) * cpx + (orig >> 3);
  const int bm = wg >> 3, bn = wg & 7;
  const int blockM = bm * 256;
  const int blockN = bn * 128;

  f32x4 acc[8][4];
#pragma unroll
  for (int m = 0; m < 8; m++)
#pragma unroll
    for (int n = 0; n < 4; n++) acc[m][n] = (f32x4){0.f, 0.f, 0.f, 0.f};

  // staging: 6 gl_lds/thread. Wave w: A rows [w*64, w*64+64) as 4 chunks of
  // 16 rows; B rows [w*32, w*32+32) as 2 chunks. lane -> row +(l>>2), phys
  // slot l&3; global source inverse-swizzled: granule (l&3)^((l>>3)&3)
  // (all chunk bases are multiples of 16, so (row>>1)&3 == (l>>3)&3).
  const int sg = (l & 3) ^ ((l >> 3) & 3);
  const unsigned short* pA[4];
#pragma unroll
  for (int c = 0; c < 4; c++)
    pA[c] = A16 + (size_t)(blockM + w * 64 + c * 16 + (l >> 2)) * DM + sg * 8;
  const unsigned short* pB[2];
#pragma unroll
  for (int c = 0; c < 2; c++)
    pB[c] = Bt16 + (size_t)(blockN + w * 32 + c * 16 + (l >> 2)) * DM + sg * 8;

  auto stage = [&](int tt, int buf) {
#pragma unroll
    for (int c = 0; c < 4; c++)
      gl_lds16(pA[c] + (size_t)tt * 32, &lds[buf * 12288 + (w * 64 + c * 16) * 32]);
#pragma unroll
    for (int c = 0; c < 2; c++)
      gl_lds16(pB[c] + (size_t)tt * 32, &lds[buf * 12288 + 8192 + (w * 32 + c * 16) * 32]);
  };

  stage(0, 0);
  __syncthreads();

  for (int t = 0; t < NT; ++t) {
    const int cur = t & 1;
    if (t + 1 < NT) stage(t + 1, cur ^ 1);  // issue next-tile loads FIRST

    bf16x8 aq[8], bq[4];
#pragma unroll
    for (int mf = 0; mf < 8; mf++) {
      const int r = wm * 128 + mf * 16 + lo;
      aq[mf] = *(const bf16x8*)(&lds[cur * 12288 + r * 32 + (hi ^ ((r >> 1) & 3)) * 8]);
    }
#pragma unroll
    for (int nf = 0; nf < 4; nf++) {
      const int r = wn * 64 + nf * 16 + lo;
      bq[nf] = *(const bf16x8*)(&lds[cur * 12288 + 8192 + r * 32 + (hi ^ ((r >> 1) & 3)) * 8]);
    }
#pragma unroll
    for (int mf = 0; mf < 8; mf++)
#pragma unroll
      for (int nf = 0; nf < 4; nf++)
        acc[mf][nf] = __builtin_amdgcn_mfma_f32_16x16x32_bf16(
            bq[nf], aq[mf], acc[mf][nf], 0, 0, 0);

    __syncthreads();  // single drain per K-tile
  }

  // epilogue: swapped mfma(B,A) mapping (r7/r8-verified):
  // row = blockM + wm*128 + mf*16 + lo; col = blockN + wn*64 + nf*16 + hi*4 + j
#pragma unroll
  for (int mf = 0; mf < 8; mf++) {
    const int row = blockM + wm * 128 + mf * 16 + lo;
    if (MODE == 1 && row >= Mvalid) continue;
#pragma unroll
    for (int nf = 0; nf < 4; nf++) {
      const int col = blockN + wn * 64 + nf * 16 + hi * 4;
      const float4 bv = *(const float4*)(bias + col);
      if (MODE == 0) {
        ushort4 o;
        o.x = f2bf(acc[mf][nf][0] + bv.x);
        o.y = f2bf(acc[mf][nf][1] + bv.y);
        o.z = f2bf(acc[mf][nf][2] + bv.z);
        o.w = f2bf(acc[mf][nf][3] + bv.w);
        *(ushort4*)(outb + (size_t)row * DM + col) = o;
      } else {
        float4 o;
        o.x = acc[mf][nf][0] + bv.x;
        o.y = acc[mf][nf][1] + bv.y;
        o.z = acc[mf][nf][2] + bv.z;
        o.w = acc[mf][nf][3] + bv.w;
        *(float4*)(outf + (size_t)row * DM + col) = o;
      }
    }
  }
}

// ---------------- scan phase A (vectorized: 8 ch/thread) ----------------
__global__ void k_scan_partial(const unsigned short* __restrict__ proj,
                               const float* __restrict__ logit,
                               const float* __restrict__ z0,
                               float* __restrict__ chunkend) {
  const int b = blockIdx.x >> 6, c = blockIdx.x & 63;
  const int ch0 = threadIdx.x * 8;
  const float a = 1.f / (1.f + expf(-logit[ch0 >> 6]));
  const int t0 = c * CL;
  const unsigned short* p = proj + (size_t)(b * T + t0) * DM + ch0;
  float pprev[8], s[8];
  if (t0 == 0) {
#pragma unroll
    for (int k = 0; k < 8; k++) pprev[k] = z0[ch0 + k];
  } else {
    bf16x8 v = *(const bf16x8*)(p - DM);
#pragma unroll
    for (int k = 0; k < 8; k++) pprev[k] = bf2f((unsigned short)v[k]);
  }
#pragma unroll
  for (int k = 0; k < 8; k++) s[k] = 0.f;
  for (int j = 0; j < CL; j++) {
    bf16x8 v = *(const bf16x8*)(p + (size_t)j * DM);
#pragma unroll
    for (int k = 0; k < 8; k++) {
      float pv = bf2f((unsigned short)v[k]);
      s[k] = a * s[k] + (1.f - a) * (pv - pprev[k]);
      pprev[k] = pv;
    }
  }
  float* o = chunkend + (size_t)(b * NCH + c) * DM + ch0;
#pragma unroll
  for (int k = 0; k < 4; k++) ((float2*)o)[k] = make_float2(s[2 * k], s[2 * k + 1]);
}

// ---------------- scan phase B (vectorized: 4 ch/thread) ----------------
__global__ void k_scan_combine(const float* __restrict__ chunkend,
                               const float* __restrict__ logit,
                               const float* __restrict__ v0,
                               float* __restrict__ enter) {
  const int b = blockIdx.x;
  const int ch0 = threadIdx.x * 4;
  const float a = 1.f / (1.f + expf(-logit[ch0 >> 6]));
  const float a2 = a * a, a4 = a2 * a2, a8 = a4 * a4, a16 = a8 * a8, a32 = a16 * a16;
  const float aL = a32 * a32;  // a^64
  float4 e = *(const float4*)(v0 + ch0);
  *(float4*)(enter + (size_t)(b * NCH) * DM + ch0) = e;
  for (int c = 1; c < NCH; c++) {
    const float4 ce = *(const float4*)(chunkend + (size_t)(b * NCH + c - 1) * DM + ch0);
    e.x = aL * e.x + ce.x;
    e.y = aL * e.y + ce.y;
    e.z = aL * e.z + ce.z;
    e.w = aL * e.w + ce.w;
    *(float4*)(enter + (size_t)(b * NCH + c) * DM + ch0) = e;
  }
}

// ---------------- scan phase C (vectorized: 8 ch/thread) ----------------
__global__ void k_scan_final(const unsigned short* __restrict__ proj,
                             const float* __restrict__ logit,
                             const float* __restrict__ z0,
                             const float* __restrict__ v0,
                             const float* __restrict__ enter,
                             unsigned short* __restrict__ S) {
  const int b = blockIdx.x >> 6, c = blockIdx.x & 63;
  const int ch0 = threadIdx.x * 8;
  const float a = 1.f / (1.f + expf(-logit[ch0 >> 6]));
  const int t0 = c * CL;
  const unsigned short* p = proj + (size_t)(b * T + t0) * DM + ch0;
  unsigned short* so = S + (size_t)(b * (T + 1) + t0 + 1) * DM + ch0;
  float pprev[8], s[8];
  if (t0 == 0) {
#pragma unroll
    for (int k = 0; k < 8; k++) pprev[k] = z0[ch0 + k];
  } else {
    bf16x8 v = *(const bf16x8*)(p - DM);
#pragma unroll
    for (int k = 0; k < 8; k++) pprev[k] = bf2f((unsigned short)v[k]);
  }
  {
    const float* e = enter + (size_t)(b * NCH + c) * DM + ch0;
#pragma unroll
    for (int k = 0; k < 8; k++) s[k] = e[k];
  }
  if (c == 0) {
    bf16x8 r;
#pragma unroll
    for (int k = 0; k < 8; k++) r[k] = (short)f2bf(v0[ch0 + k]);
    *(bf16x8*)(S + (size_t)b * (T + 1) * DM + ch0) = r;  // row 0 = v0
  }
  for (int j = 0; j < CL; j++) {
    bf16x8 v = *(const bf16x8*)(p + (size_t)j * DM);
    bf16x8 r;
#pragma unroll
    for (int k = 0; k < 8; k++) {
      float pv = bf2f((unsigned short)v[k]);
      s[k] = a * s[k] + (1.f - a) * (pv - pprev[k]);
      pprev[k] = pv;
      r[k] = (short)f2bf(s[k]);
    }
    *(bf16x8*)(so + (size_t)j * DM) = r;
  }
}

extern "C" void kernel_launch(void* const* d_in, const int* in_sizes, int n_in,
                              void* d_out, int out_size, void* d_ws, size_t ws_size,
                              hipStream_t stream) {
  const float* inputs = (const float*)d_in[0];
  const float* z0     = (const float*)d_in[1];
  const float* W_in   = (const float*)d_in[2];
  const float* b_in   = (const float*)d_in[3];
  const float* W_out  = (const float*)d_in[4];
  const float* b_out  = (const float*)d_in[5];
  const float* slogit = (const float*)d_in[6];
  const float* v0     = (const float*)d_in[7];
  float* out = (float*)d_out;

  char* ws = (char*)d_ws;
  unsigned short* X16   = (unsigned short*)(ws);                 // 67,108,864 B
  unsigned short* P16   = (unsigned short*)(ws + 67108864);      // 67,108,864 B
  unsigned short* S16   = (unsigned short*)(ws + 134217728);     // 67,633,152 B (33024 rows)
  unsigned short* WTin  = (unsigned short*)(ws + 201850880);     // 2,097,152 B
  unsigned short* WTout = (unsigned short*)(ws + 203948032);     // 2,097,152 B
  float* chunkend       = (float*)(ws + 206045184);              // 2,097,152 B
  float* enter          = (float*)(ws + 208142336);              // 2,097,152 B

  // 1. convert inputs to bf16
  k_cvt_x<<<32768, 256, 0, stream>>>((const float4*)inputs, (ushort4*)X16);
  // 2. transpose+convert both weights
  k_transpose<<<dim3(32, 32, 2), 256, 0, stream>>>(W_in, W_out, WTin, WTout);
  // 3. GEMM1: proj = inputs @ W_in + b_in (bf16 out), 128x8 = 1024 wgs
  k_gemm<0><<<dim3((M1 / 256) * 8), 256, 0, stream>>>(X16, WTin, b_in, P16, nullptr, M1);
  // 4. scan: temporal diff + exponential smoothing (vectorized)
  k_scan_partial<<<dim3(BATCH * NCH), 128, 0, stream>>>(P16, slogit, z0, chunkend);
  k_scan_combine<<<dim3(BATCH), 256, 0, stream>>>(chunkend, slogit, v0, enter);
  k_scan_final<<<dim3(BATCH * NCH), 128, 0, stream>>>(P16, slogit, z0, v0, enter, S16);
  // (pad rows of S16 are unwritten poison: finite bf16, outputs row-guarded)
  // 5. GEMM2: out = S @ W_out + b_out (fp32, 32776 valid of 33024), 129x8 = 1032 wgs
  k_gemm<1><<<dim3((M2P / 256) * 8), 256, 0, stream>>>(S16, WTout, b_out, nullptr, out, M2);
}